// Round 13
// baseline (100.358 us; speedup 1.0000x reference)
//
#include <hip/hip_runtime.h>
#include <hip/hip_bf16.h>

typedef __attribute__((ext_vector_type(8))) short bf16x8;
typedef __attribute__((ext_vector_type(4))) float f32x4;
typedef unsigned short u16;

#define D_MODEL 1024
#define ROWS 32            // rows per block: grid 512, 2 blocks/CU, 8 waves each

// Packed-weight geometry: fragments of 512 bf16 (64 lanes x 8), frag(nt,kt).
// Phase-1 B: 17 col-tiles (16 down + 1 gate-padded) x 32 k-tiles (K=1024).
// Phase-2 B: 64 col-tiles (N=1024)                x  8 k-tiles (K=256).
#define WD_FRAGS (17 * 32)
#define WU_FRAGS (64 * 8)
#define WD_ELEMS (WD_FRAGS * 512)   // 278528 bf16
#define WU_ELEMS (WU_FRAGS * 512)   // 262144 bf16

// LDS map (bytes), total 49664. Phase 1 uses NO LDS (x read as A-frags from global).
//  ds (gated-down, 32x512B swizzled) = [0,16384)
//  tb (transpose, 32x260 f32 = 33280 B) = [16384,49664)
#define LDS_TOTAL 49664
#define TB_STRIDE 260

__device__ __forceinline__ u16 f2bf(float f) {  // RNE f32 -> bf16 (prep/pack paths)
  union { float f; unsigned u; } v; v.f = f;
  return (u16)((v.u + 0x7fffu + ((v.u >> 16) & 1u)) >> 16);
}

__device__ __forceinline__ u16 bfu(float f) {   // HW-converted RNE bf16
  __hip_bfloat16 b = __float2bfloat16(f);
  return *reinterpret_cast<u16*>(&b);
}

// two float4 (8 consecutive fp32 of one x row) -> one A-fragment half
__device__ __forceinline__ bf16x8 cvt8(float4 v0, float4 v1) {
  bf16x8 h;
  h[0] = (short)bfu(v0.x); h[1] = (short)bfu(v0.y);
  h[2] = (short)bfu(v0.z); h[3] = (short)bfu(v0.w);
  h[4] = (short)bfu(v1.x); h[5] = (short)bfu(v1.y);
  h[6] = (short)bfu(v1.z); h[7] = (short)bfu(v1.w);
  return h;
}

// Pack per-expert weights into MFMA B-fragment order (bf16).
// Fragment element (lane, j) holds B[k = kt*32 + (lane>>4)*8 + j][col = nt*16 + (lane&15)].
__global__ void lora_prep(const float* __restrict__ Wd, const float* __restrict__ Wu,
                          const float* __restrict__ Wg,
                          u16* __restrict__ wd_pack, u16* __restrict__ wu_pack) {
  int idx = blockIdx.x * 256 + threadIdx.x;
  if (idx < WD_ELEMS) {
    int frag = idx >> 9, w = idx & 511;
    int lane = w >> 3, j = w & 7;
    int nt = frag >> 5, kt = frag & 31;
    int k = kt * 32 + (lane >> 4) * 8 + j;        // 0..1023
    int col = nt * 16 + (lane & 15);              // 0..271
    float v;
    if (col < 256) {
      v = Wd[((col >> 6) * 1024 + k) * 64 + (col & 63)];   // W_down[e][k][a]
    } else {
      int c2 = col - 256;
      v = (c2 < 4) ? Wg[k * 4 + c2] : 0.f;                 // W_gate[k][e], zero-padded
    }
    wd_pack[idx] = f2bf(v);
  } else if (idx < WD_ELEMS + WU_ELEMS) {
    int u = idx - WD_ELEMS;
    int frag = u >> 9, w = u & 511;
    int lane = w >> 3, j = w & 7;
    int nt = frag >> 3, kt = frag & 7;
    int k = kt * 32 + (lane >> 4) * 8 + j;        // 0..255 (= e*64 + a)
    int col = nt * 16 + (lane & 15);              // 0..1023
    wu_pack[u] = f2bf(Wu[((k >> 6) * 64 + (k & 63)) * 1024 + col]);  // W_up[e][a][d]
  }
}

__global__ __launch_bounds__(512, 4) void lora_main(
    const float* __restrict__ x, const float* __restrict__ b_gate,
    const u16* __restrict__ wd_pack, const u16* __restrict__ wu_pack,
    float* __restrict__ out) {
  extern __shared__ char smem[];

  const int tid = threadIdx.x;     // 0..511
  const int lane = tid & 63;
  const int wave = tid >> 6;       // 0..7
  const int l15 = lane & 15;
  const int lg = lane >> 4;
  const size_t row0 = (size_t)blockIdx.x * ROWS;
  const float* xblk = x + row0 * D_MODEL;
  // per-lane A-frag base: rows l15 (r=0) and 16+l15 (r=1), k-offset lg*8
  const float* xr0 = xblk + (size_t)l15 * D_MODEL + lg * 8;
  const float* xr1 = xr0 + 16 * D_MODEL;

  f32x4 acc[2][2];   // [col-tile i][row-frag r]; wave w owns tiles {w, w+8}
  f32x4 accg[2];     // gate tile (nt=16) — ALL waves (identical), in-reg softmax
#pragma unroll
  for (int i = 0; i < 2; ++i)
#pragma unroll
    for (int r = 0; r < 2; ++r) acc[i][r] = {0.f, 0.f, 0.f, 0.f};
#pragma unroll
  for (int r = 0; r < 2; ++r) accg[r] = {0.f, 0.f, 0.f, 0.f};

  // ---- phase 1: down[32][256] + gate logits. K = 1024, barrier-free:
  // A-frags read DIRECTLY from global x (two float4 per row-frag) + HW cvt;
  // B-frags ring-3 depth-2 prefetch (R5-proven).
  bf16x8 bq[3][2];
  bf16x8 gq[3];
#pragma unroll 1
  for (int c = 0; c < 4; ++c) {
#pragma unroll
    for (int pk = 0; pk < 2; ++pk) {
      int ktg = c * 8 + pk;
#pragma unroll
      for (int i = 0; i < 2; ++i)
        bq[pk][i] = *(const bf16x8*)(wd_pack + (size_t)((wave + i * 8) * 32 + ktg) * 512 + lane * 8);
      gq[pk] = *(const bf16x8*)(wd_pack + (size_t)(512 + ktg) * 512 + lane * 8);
    }
#pragma unroll
    for (int ks = 0; ks < 8; ++ks) {
      const int ktg = c * 8 + ks;
      const int s = ks % 3;
      if (ks < 6) {  // prefetch B for ks+2
        int ktg2 = c * 8 + ks + 2;
        int s2 = (ks + 2) % 3;
#pragma unroll
        for (int i = 0; i < 2; ++i)
          bq[s2][i] = *(const bf16x8*)(wd_pack + (size_t)((wave + i * 8) * 32 + ktg2) * 512 + lane * 8);
        gq[s2] = *(const bf16x8*)(wd_pack + (size_t)(512 + ktg2) * 512 + lane * 8);
      }
      // A-frags straight from x (L3-resident; L1 absorbs 8x wave redundancy)
      float4 p00 = *(const float4*)(xr0 + ktg * 32);
      float4 p01 = *(const float4*)(xr0 + ktg * 32 + 4);
      float4 p10 = *(const float4*)(xr1 + ktg * 32);
      float4 p11 = *(const float4*)(xr1 + ktg * 32 + 4);
      bf16x8 a[2];
      a[0] = cvt8(p00, p01);
      a[1] = cvt8(p10, p11);
#pragma unroll
      for (int i = 0; i < 2; ++i)
#pragma unroll
        for (int r = 0; r < 2; ++r)
          acc[i][r] = __builtin_amdgcn_mfma_f32_16x16x32_bf16(a[r], bq[s][i], acc[i][r], 0, 0, 0);
#pragma unroll
      for (int r = 0; r < 2; ++r)
        accg[r] = __builtin_amdgcn_mfma_f32_16x16x32_bf16(a[r], gq[s], accg[r], 0, 0, 0);
    }
  }

  // ---- gate softmax fully in registers (R11-proven).
  // accg C-layout: expert = l15 (0..3 valid, rest zero-pad), row = r*16+lg*4+j.
  float gown[2][4];
  {
    const float bg = b_gate[l15 & 3];
#pragma unroll
    for (int r = 0; r < 2; ++r)
#pragma unroll
      for (int j = 0; j < 4; ++j) {
        float v = accg[r][j] + bg;
        float m1 = fmaxf(v, __shfl_xor(v, 1));
        float mx = fmaxf(m1, __shfl_xor(m1, 2));
        float ex = expf(v - mx);
        float s1 = ex + __shfl_xor(ex, 1);
        float sm = s1 + __shfl_xor(s1, 2);
        gown[r][j] = ex / sm;
      }
  }

  // ---- apply gate, pack down to bf16 into ds (swizzled, k=e*64+a).
  // Thread needs expert e=(wave+8i)>>2 weights for rows (lg,r,j): lane lg*16+e has them.
  char* ds = smem;
#pragma unroll
  for (int i = 0; i < 2; ++i) {
    int nt = wave + i * 8;
    int col = nt * 16 + l15;
    int e = nt >> 2;
    int src = lg * 16 + e;
    int cb = col * 2;
#pragma unroll
    for (int r = 0; r < 2; ++r) {
#pragma unroll
      for (int j = 0; j < 4; ++j) {
        float gv = __shfl(gown[r][j], src);
        int row = r * 16 + lg * 4 + j;
        float val = acc[i][r][j] * gv;
        *(u16*)(ds + row * 512 + (cb ^ ((row & 7) << 4))) = f2bf(val);
      }
    }
  }
  __syncthreads();   // the single phase-1 -> phase-2 barrier

  // ---- phase 2: out[32][1024] = down_g[32][256] @ Wup, N in 4 chunks of 256.
  // (R11-proven.) Epilogue transposes through tb for contiguous float4 stores.
  float* tb = (float*)(smem + 16384);
  bf16x8 b2[3][2];
#pragma unroll 1
  for (int nc = 0; nc < 4; ++nc) {
    f32x4 acc2[2][2];
#pragma unroll
    for (int i = 0; i < 2; ++i)
#pragma unroll
      for (int r = 0; r < 2; ++r) acc2[i][r] = {0.f, 0.f, 0.f, 0.f};
#pragma unroll
    for (int pk = 0; pk < 2; ++pk)
#pragma unroll
      for (int i = 0; i < 2; ++i)
        b2[pk][i] = *(const bf16x8*)(wu_pack + (size_t)((nc * 16 + wave * 2 + i) * 8 + pk) * 512 + lane * 8);
#pragma unroll
    for (int ks = 0; ks < 8; ++ks) {
      const int s = ks % 3;
      if (ks < 6) {
        int s2 = (ks + 2) % 3;
#pragma unroll
        for (int i = 0; i < 2; ++i)
          b2[s2][i] = *(const bf16x8*)(wu_pack + (size_t)((nc * 16 + wave * 2 + i) * 8 + ks + 2) * 512 + lane * 8);
      }
      bf16x8 a[2];
#pragma unroll
      for (int r = 0; r < 2; ++r) {
        int rr = r * 16 + l15;
        int cb = (ks * 32 + lg * 8) * 2;
        a[r] = *(const bf16x8*)(ds + rr * 512 + (cb ^ ((rr & 7) << 4)));
      }
#pragma unroll
      for (int i = 0; i < 2; ++i)
#pragma unroll
        for (int r = 0; r < 2; ++r)
          acc2[i][r] = __builtin_amdgcn_mfma_f32_16x16x32_bf16(a[r], b2[s][i], acc2[i][r], 0, 0, 0);
    }
#pragma unroll
    for (int i = 0; i < 2; ++i) {
      int cl = wave * 32 + i * 16 + l15;    // col within this 256-col chunk
#pragma unroll
      for (int r = 0; r < 2; ++r)
#pragma unroll
        for (int j = 0; j < 4; ++j)
          tb[(r * 16 + lg * 4 + j) * TB_STRIDE + cl] = acc2[i][r][j];
    }
    __syncthreads();
#pragma unroll
    for (int it = 0; it < 4; ++it) {
      int flat = it * 2048 + tid * 4;       // 32 rows x 256 cols f32
      int row = flat >> 8, col = flat & 255;
      float4 v = *(const float4*)(tb + row * TB_STRIDE + col);
      *(float4*)(out + (row0 + row) * D_MODEL + nc * 256 + col) = v;
    }
    __syncthreads();
  }
}

extern "C" void kernel_launch(void* const* d_in, const int* in_sizes, int n_in,
                              void* d_out, int out_size, void* d_ws, size_t ws_size,
                              hipStream_t stream) {
  const float* x  = (const float*)d_in[0];
  const float* Wd = (const float*)d_in[1];
  const float* Wu = (const float*)d_in[2];
  const float* Wg = (const float*)d_in[3];
  const float* bg = (const float*)d_in[4];
  float* out = (float*)d_out;
  const int M = in_sizes[0] / D_MODEL;  // 16384

  u16* wd_pack = (u16*)d_ws;            // 557056 B
  u16* wu_pack = wd_pack + WD_ELEMS;    // +524288 B  (needs ~1.03 MB of ws)

  const int total = WD_ELEMS + WU_ELEMS;
  lora_prep<<<(total + 255) / 256, 256, 0, stream>>>(Wd, Wu, Wg, wd_pack, wu_pack);
  lora_main<<<M / ROWS, 512, LDS_TOTAL, stream>>>(x, bg, wd_pack, wu_pack, out);
}